// Round 1
// baseline (3549.763 us; speedup 1.0000x reference)
//
#include <hip/hip_runtime.h>
#include <math.h>

#define NN 1024
#define MEM 300
#define GB 30          // blocks per tree
#define SLICE 10       // j columns owned per block (30 blocks * 10 = 300)
#define MAXLVL 64

// ---------- agent-scope helpers (cross-XCD safe) ----------
__device__ __forceinline__ float agloadf(const float* p) {
  return __hip_atomic_load(p, __ATOMIC_RELAXED, __HIP_MEMORY_SCOPE_AGENT);
}
__device__ __forceinline__ int agloadi(const int* p) {
  return __hip_atomic_load(p, __ATOMIC_RELAXED, __HIP_MEMORY_SCOPE_AGENT);
}
__device__ __forceinline__ void agstoref(float* p, float v) {
  __hip_atomic_store(p, v, __ATOMIC_RELAXED, __HIP_MEMORY_SCOPE_AGENT);
}
__device__ __forceinline__ void agstorei(int* p, int v) {
  __hip_atomic_store(p, v, __ATOMIC_RELAXED, __HIP_MEMORY_SCOPE_AGENT);
}

// per-tree grid barrier over GB blocks (agent-scope atomics + fences)
__device__ __forceinline__ void treebar(int* bar, int t) {
  __syncthreads();
  if (threadIdx.x == 0) {
    int* cnt = bar + t * 32;
    int* gen = bar + t * 32 + 16;
    __threadfence();
    int g = __hip_atomic_load(gen, __ATOMIC_RELAXED, __HIP_MEMORY_SCOPE_AGENT);
    int v = __hip_atomic_fetch_add(cnt, 1, __ATOMIC_ACQ_REL, __HIP_MEMORY_SCOPE_AGENT);
    if (v == GB - 1) {
      __hip_atomic_store(cnt, 0, __ATOMIC_RELAXED, __HIP_MEMORY_SCOPE_AGENT);
      __hip_atomic_fetch_add(gen, 1, __ATOMIC_RELEASE, __HIP_MEMORY_SCOPE_AGENT);
    } else {
      while (__hip_atomic_load(gen, __ATOMIC_ACQUIRE, __HIP_MEMORY_SCOPE_AGENT) == g) { }
    }
    __threadfence();
  }
  __syncthreads();
}

__device__ __forceinline__ float sigmoidf_(float x) {
  return 1.0f / (1.0f + expf(-x));
}

// ---------- K1: x-projections  xiou = emb[sent]@Wioux.T+b ; xf = emb[sent]@Wfx.T+b ----------
#define K1_NT 32
#define K1_CT 48
__global__ __launch_bounds__(256, 1)
void proj_kernel(const int* __restrict__ lsent, const int* __restrict__ rsent,
                 const float* __restrict__ emb,
                 const float* __restrict__ Wioux, const float* __restrict__ bioux,
                 const float* __restrict__ Wfx, const float* __restrict__ bfx,
                 float* __restrict__ xiou, float* __restrict__ xf) {
  __shared__ float xt[K1_NT][300];
  __shared__ float wt[K1_CT][100];
  const int tid = threadIdx.x;
  const int g0 = blockIdx.y * K1_NT;      // global node-id (tree-major, 2048)
  const int c0 = blockIdx.x * K1_CT;      // output col in [0,1200)

  for (int e = tid; e < K1_NT * 300; e += 256) {
    int nn = e / 300, k = e - nn * 300;
    int g = g0 + nn;
    int t = g >> 10, n = g & (NN - 1);
    int s = (t ? rsent : lsent)[n];
    xt[nn][k] = emb[(size_t)s * 300 + k];
  }

  const int a = tid >> 4;   // 0..15 -> nodes {a, a+16}
  const int b = tid & 15;   // 0..15 -> cols {b, b+16, b+32}
  float acc00 = 0, acc01 = 0, acc02 = 0, acc10 = 0, acc11 = 0, acc12 = 0;

  for (int kc = 0; kc < 300; kc += 100) {
    __syncthreads();
    for (int e = tid; e < K1_CT * 100; e += 256) {
      int cc = e / 100, k = e - cc * 100;
      int col = c0 + cc;
      wt[cc][k] = (col < 900) ? Wioux[(size_t)col * 300 + kc + k]
                              : Wfx[(size_t)(col - 900) * 300 + kc + k];
    }
    __syncthreads();
    #pragma unroll
    for (int k4 = 0; k4 < 25; ++k4) {
      float4 x0 = *(const float4*)&xt[a][kc + k4 * 4];
      float4 x1 = *(const float4*)&xt[a + 16][kc + k4 * 4];
      float4 w0 = *(const float4*)&wt[b][k4 * 4];
      float4 w1 = *(const float4*)&wt[b + 16][k4 * 4];
      float4 w2 = *(const float4*)&wt[b + 32][k4 * 4];
      acc00 += x0.x * w0.x + x0.y * w0.y + x0.z * w0.z + x0.w * w0.w;
      acc01 += x0.x * w1.x + x0.y * w1.y + x0.z * w1.z + x0.w * w1.w;
      acc02 += x0.x * w2.x + x0.y * w2.y + x0.z * w2.z + x0.w * w2.w;
      acc10 += x1.x * w0.x + x1.y * w0.y + x1.z * w0.z + x1.w * w0.w;
      acc11 += x1.x * w1.x + x1.y * w1.y + x1.z * w1.z + x1.w * w1.w;
      acc12 += x1.x * w2.x + x1.y * w2.y + x1.z * w2.z + x1.w * w2.w;
    }
  }

  float accs[2][3] = {{acc00, acc01, acc02}, {acc10, acc11, acc12}};
  for (int ni = 0; ni < 2; ++ni) {
    for (int ci = 0; ci < 3; ++ci) {
      int g = g0 + a + 16 * ni;
      int col = c0 + b + 16 * ci;
      int t = g >> 10, n = g & (NN - 1);
      float v = accs[ni][ci];
      if (col < 900) xiou[((size_t)t * NN + n) * 900 + col] = v + bioux[col];
      else           xf[((size_t)t * NN + n) * 300 + (col - 900)] = v + bfx[col - 900];
    }
  }
}

// ---------- K2: level computation + level-parallel tree-LSTM scan ----------
__global__ __launch_bounds__(256, 1)
void scan_kernel(const int* __restrict__ lparents, const int* __restrict__ rparents,
                 const float* __restrict__ Wiouh, const float* __restrict__ biouh,
                 const float* __restrict__ Wfh, const float* __restrict__ bfh,
                 const float* __restrict__ xiou, const float* __restrict__ xf,
                 float* hsum, float* fcsum, float* cbuf,
                 int* lvl, int* lcnt, int* cur, int* chg, int* maxl,
                 int* bar, int* list, float* out) {
  const int tid = threadIdx.x;
  const int t = (blockIdx.x < GB) ? 0 : 1;
  const int big = blockIdx.x - t * GB;
  const int j0 = big * SLICE;

  // dot-thread layout: tid<80 : slot = tid>>3 in [0,10), ks = tid&7 -> k-chunk
  const int slot = tid >> 3;
  const int ks = tid & 7;
  const int k0 = (ks < 4) ? ks * 38 : 152 + (ks - 4) * 37;
  const int klen = (ks < 4) ? 38 : 37;
  const bool dotA = (tid < 80);

  const int* parents = t ? rparents : lparents;
  const float* xiouT = xiou + (size_t)t * NN * 900;
  const float* xfT = xf + (size_t)t * NN * MEM;
  float* hsumT = hsum + (size_t)t * NN * MEM;
  float* fcsumT = fcsum + (size_t)t * NN * MEM;
  float* cbufT = cbuf + (size_t)t * NN * MEM;
  float* houtT = out + 5 + (size_t)t * NN * MEM;
  int* lvlT = lvl + t * NN;
  const int* listT = list + t * NN;

  // register-resident weight slices: 30 Wiouh rows (as 3x10 triples) + 10 Wfh rows
  float wa0[38], wa1[38], wa2[38], wb[38];
  #pragma unroll
  for (int i = 0; i < 38; ++i) { wa0[i] = 0.f; wa1[i] = 0.f; wa2[i] = 0.f; wb[i] = 0.f; }
  if (dotA) {
    const float* r0 = Wiouh + (size_t)(0 * MEM + j0 + slot) * MEM;
    const float* r1 = Wiouh + (size_t)(1 * MEM + j0 + slot) * MEM;
    const float* r2 = Wiouh + (size_t)(2 * MEM + j0 + slot) * MEM;
    const float* r3 = Wfh + (size_t)(j0 + slot) * MEM;
    for (int i = 0; i < klen; ++i) {
      wa0[i] = r0[k0 + i]; wa1[i] = r1[k0 + i]; wa2[i] = r2[k0 + i]; wb[i] = r3[k0 + i];
    }
  }

  __shared__ float vbuf[4][304];
  __shared__ float dots[4][32];
  __shared__ int nodeId[4];
  __shared__ float bI[SLICE], bO[SLICE], bU[SLICE], bF[SLICE];
  __shared__ int offs[MAXLVL];
  __shared__ int cnts[MAXLVL];
  __shared__ int mlS;

  if (tid < SLICE) {
    bI[tid] = biouh[j0 + tid];
    bO[tid] = biouh[300 + j0 + tid];
    bU[tid] = biouh[600 + j0 + tid];
    bF[tid] = bfh[j0 + tid];
  }

  // ---- levels: Bellman-Ford with early exit (lvl[n] = longest chain below n) ----
  const int myn = big * 256 + tid;   // blocks 0..3 cover all nodes
  for (int iter = 0; iter < MAXLVL; ++iter) {
    if (myn < NN - 1) {
      int L = agloadi(lvlT + myn);
      int v = L + 1;
      int p = parents[myn];
      int old = atomicMax(lvlT + p, v);
      if (old < v) agstorei(chg + t * MAXLVL + iter, 1);
    }
    treebar(bar, t);
    if (agloadi(chg + t * MAXLVL + iter) == 0) break;
  }
  if (myn < NN) {
    int L = min(agloadi(lvlT + myn), MAXLVL - 1);
    atomicMax(maxl + t, L);
    atomicAdd(lcnt + t * MAXLVL + L, 1);
  }
  treebar(bar, t);
  if (tid == 0) mlS = agloadi(maxl + t);
  if (tid < MAXLVL) cnts[tid] = agloadi(lcnt + t * MAXLVL + tid);
  __syncthreads();
  const int ml = mlS;
  if (tid == 0) {
    int run = 0;
    for (int l = 0; l < MAXLVL; ++l) { offs[l] = run; run += cnts[l]; }
  }
  __syncthreads();
  if (myn < NN) {
    int L = min(agloadi(lvlT + myn), MAXLVL - 1);
    int pos = atomicAdd(cur + t * MAXLVL + L, 1);
    agstorei(list + t * NN + offs[L] + pos, myn);
  }
  treebar(bar, t);

  // ---- main level loop: phase L = { B(L-1) ; A(L) } ----
  for (int L = 0; L <= ml; ++L) {
    if (L > 0) {
      // B-pass for level L-1: f = sig(Wfh@h + bfh + xf[p]); fcsum[p] += f*c
      const int c0l = offs[L - 1], cn = cnts[L - 1];
      for (int base = 0; base < cn; base += 4) {
        const int nb = min(4, cn - base);
        for (int e = tid; e < nb * 304; e += 256) {
          int bb = e / 304, k = e - bb * 304;
          int n = agloadi(listT + c0l + base + bb);
          vbuf[bb][k] = (k < MEM) ? agloadf(houtT + (size_t)n * MEM + k) : 0.f;
        }
        if (tid < nb) nodeId[tid] = agloadi(listT + c0l + base + tid);
        __syncthreads();
        if (dotA) {
          for (int bb = 0; bb < nb; ++bb) {
            float acc = 0.f;
            #pragma unroll
            for (int i = 0; i < 38; ++i) acc += wb[i] * vbuf[bb][k0 + i];
            acc += __shfl_xor(acc, 1);
            acc += __shfl_xor(acc, 2);
            acc += __shfl_xor(acc, 4);
            if (ks == 0) dots[bb][slot] = acc;
          }
        }
        __syncthreads();
        if (tid < nb * SLICE) {
          int bb = tid / SLICE, j = tid - bb * SLICE;
          int n = nodeId[bb];
          int p = parents[n];
          if (p != n) {  // skip root (self-parent; fcsum[root] never read again)
            float f = sigmoidf_(dots[bb][j] + bF[j] + xfT[(size_t)p * MEM + j0 + j]);
            float cadd = f * cbufT[(size_t)n * MEM + j0 + j];
            atomicAdd(fcsumT + (size_t)p * MEM + j0 + j, cadd);
          }
        }
        __syncthreads();
      }
      __syncthreads();
    }
    // A-pass for level L: iou = xiou[n] + Wiouh@hsum[n] + biouh -> h
    {
      const int c0l = offs[L], cn = cnts[L];
      for (int base = 0; base < cn; base += 4) {
        const int nb = min(4, cn - base);
        for (int e = tid; e < nb * 304; e += 256) {
          int bb = e / 304, k = e - bb * 304;
          int n = agloadi(listT + c0l + base + bb);
          vbuf[bb][k] = (k < MEM) ? agloadf(hsumT + (size_t)n * MEM + k) : 0.f;
        }
        if (tid < nb) nodeId[tid] = agloadi(listT + c0l + base + tid);
        __syncthreads();
        if (dotA) {
          for (int bb = 0; bb < nb; ++bb) {
            float aI = 0.f, aO = 0.f, aU = 0.f;
            #pragma unroll
            for (int i = 0; i < 38; ++i) {
              float v = vbuf[bb][k0 + i];
              aI += wa0[i] * v; aO += wa1[i] * v; aU += wa2[i] * v;
            }
            aI += __shfl_xor(aI, 1); aO += __shfl_xor(aO, 1); aU += __shfl_xor(aU, 1);
            aI += __shfl_xor(aI, 2); aO += __shfl_xor(aO, 2); aU += __shfl_xor(aU, 2);
            aI += __shfl_xor(aI, 4); aO += __shfl_xor(aO, 4); aU += __shfl_xor(aU, 4);
            if (ks == 0) {
              dots[bb][slot] = aI;
              dots[bb][SLICE + slot] = aO;
              dots[bb][2 * SLICE + slot] = aU;
            }
          }
        }
        __syncthreads();
        if (tid < nb * SLICE) {
          int bb = tid / SLICE, j = tid - bb * SLICE;
          int n = nodeId[bb];
          const float* xr = xiouT + (size_t)n * 900;
          float i_ = sigmoidf_(dots[bb][j] + bI[j] + xr[j0 + j]);
          float o_ = sigmoidf_(dots[bb][SLICE + j] + bO[j] + xr[300 + j0 + j]);
          float u_ = tanhf(dots[bb][2 * SLICE + j] + bU[j] + xr[600 + j0 + j]);
          float fc = agloadf(fcsumT + (size_t)n * MEM + j0 + j);
          float c = i_ * u_ + fc;
          float h = o_ * tanhf(c);
          cbufT[(size_t)n * MEM + j0 + j] = c;                 // block-local reuse
          agstoref(houtT + (size_t)n * MEM + j0 + j, h);       // cross-block visible
          int p = parents[n];
          if (p != n) atomicAdd(hsumT + (size_t)p * MEM + j0 + j, h);
        }
        __syncthreads();
      }
    }
    treebar(bar, t);
  }
}

// ---------- K3: similarity head ----------
__global__ __launch_bounds__(256, 1)
void head_kernel(const float* __restrict__ Wwh, const float* __restrict__ bwh,
                 const float* __restrict__ Wwp, const float* __restrict__ bwp,
                 float* out) {
  __shared__ float vd[600];
  __shared__ float hid[200];
  __shared__ float sL[5];
  const int tid = threadIdx.x;
  for (int e = tid; e < 300; e += 256) {
    float lv = out[5 + 1023 * 300 + e];
    float rv = out[5 + 307200 + 1023 * 300 + e];
    vd[e] = lv * rv;
    vd[300 + e] = fabsf(lv - rv);
  }
  __syncthreads();
  if (tid < 200) {
    float acc = bwh[tid];
    const float* wr = Wwh + (size_t)tid * 600;
    for (int k = 0; k < 600; ++k) acc += vd[k] * wr[k];
    hid[tid] = sigmoidf_(acc);
  }
  __syncthreads();
  if (tid < 5) {
    float acc = bwp[tid];
    const float* wr = Wwp + (size_t)tid * 200;
    for (int k = 0; k < 200; ++k) acc += hid[k] * wr[k];
    sL[tid] = acc;
  }
  __syncthreads();
  if (tid == 0) {
    float m = sL[0];
    for (int c = 1; c < 5; ++c) m = fmaxf(m, sL[c]);
    float s = 0.f;
    for (int c = 0; c < 5; ++c) s += expf(sL[c] - m);
    float lz = m + logf(s);
    for (int c = 0; c < 5; ++c) out[c] = sL[c] - lz;
  }
}

extern "C" void kernel_launch(void* const* d_in, const int* in_sizes, int n_in,
                              void* d_out, int out_size, void* d_ws, size_t ws_size,
                              hipStream_t stream) {
  const int* lsent = (const int*)d_in[0];
  const int* lparents = (const int*)d_in[1];
  const int* rsent = (const int*)d_in[2];
  const int* rparents = (const int*)d_in[3];
  // d_in[4] = calculate_sim (unused)
  const float* emb = (const float*)d_in[5];
  const float* Wioux = (const float*)d_in[6];
  const float* bioux = (const float*)d_in[7];
  const float* Wiouh = (const float*)d_in[8];
  const float* biouh = (const float*)d_in[9];
  const float* Wfx = (const float*)d_in[10];
  const float* bfx = (const float*)d_in[11];
  const float* Wfh = (const float*)d_in[12];
  const float* bfh = (const float*)d_in[13];
  const float* Wwh = (const float*)d_in[14];
  const float* bwh = (const float*)d_in[15];
  const float* Wwp = (const float*)d_in[16];
  const float* bwp = (const float*)d_in[17];
  float* out = (float*)d_out;

  char* ws = (char*)d_ws;
  float* hsum = (float*)(ws);                    // 2*1024*300 f  (zeroed)
  float* fcsum = (float*)(ws + 2457600);         // 2*1024*300 f  (zeroed)
  int* lvl = (int*)(ws + 4915200);               // 2048 i        (zeroed)
  int* lcnt = (int*)(ws + 4923392);              // 128 i         (zeroed)
  int* cur = (int*)(ws + 4923904);               // 128 i         (zeroed)
  int* chg = (int*)(ws + 4924416);               // 128 i         (zeroed)
  int* maxl = (int*)(ws + 4924928);              // 2 i + pad     (zeroed)
  int* bar = (int*)(ws + 4924992);               // 64 i          (zeroed)
  float* xiou = (float*)(ws + 4925440);          // 2*1024*900 f
  float* xf = (float*)(ws + 12298240);           // 2*1024*300 f
  float* cbuf = (float*)(ws + 14755840);         // 2*1024*300 f
  int* list = (int*)(ws + 17213440);             // 2048 i

  hipMemsetAsync(d_ws, 0, 4925248, stream);
  proj_kernel<<<dim3(25, 64), 256, 0, stream>>>(lsent, rsent, emb, Wioux, bioux,
                                                Wfx, bfx, xiou, xf);
  scan_kernel<<<60, 256, 0, stream>>>(lparents, rparents, Wiouh, biouh, Wfh, bfh,
                                      xiou, xf, hsum, fcsum, cbuf,
                                      lvl, lcnt, cur, chg, maxl, bar, list, out);
  head_kernel<<<1, 256, 0, stream>>>(Wwh, bwh, Wwp, bwp, out);
}

// Round 2
// 1924.891 us; speedup vs baseline: 1.8441x; 1.8441x over previous
//
#include <hip/hip_runtime.h>
#include <math.h>

#define NN 1024
#define MEM 300
#define GB 30          // column-slice blocks per tree (30 * SLICE = 300)
#define NG 4           // node-group parallelism per tree
#define BPT (GB * NG)  // blocks per tree = 120
#define SLICE 10       // j columns owned per column-slice
#define MAXLVL 64

// ---------- agent-scope helpers (cross-XCD safe) ----------
__device__ __forceinline__ float agloadf(const float* p) {
  return __hip_atomic_load(p, __ATOMIC_RELAXED, __HIP_MEMORY_SCOPE_AGENT);
}
__device__ __forceinline__ int agloadi(const int* p) {
  return __hip_atomic_load(p, __ATOMIC_RELAXED, __HIP_MEMORY_SCOPE_AGENT);
}
__device__ __forceinline__ void agstoref(float* p, float v) {
  __hip_atomic_store(p, v, __ATOMIC_RELAXED, __HIP_MEMORY_SCOPE_AGENT);
}
__device__ __forceinline__ void agstorei(int* p, int v) {
  __hip_atomic_store(p, v, __ATOMIC_RELAXED, __HIP_MEMORY_SCOPE_AGENT);
}

// per-tree grid barrier over BPT blocks (agent-scope atomics + fences)
__device__ __forceinline__ void treebar(int* bar, int t) {
  __syncthreads();
  if (threadIdx.x == 0) {
    int* cnt = bar + t * 32;
    int* gen = bar + t * 32 + 16;
    __threadfence();
    int g = __hip_atomic_load(gen, __ATOMIC_RELAXED, __HIP_MEMORY_SCOPE_AGENT);
    int v = __hip_atomic_fetch_add(cnt, 1, __ATOMIC_ACQ_REL, __HIP_MEMORY_SCOPE_AGENT);
    if (v == BPT - 1) {
      __hip_atomic_store(cnt, 0, __ATOMIC_RELAXED, __HIP_MEMORY_SCOPE_AGENT);
      __hip_atomic_fetch_add(gen, 1, __ATOMIC_RELEASE, __HIP_MEMORY_SCOPE_AGENT);
    } else {
      while (__hip_atomic_load(gen, __ATOMIC_ACQUIRE, __HIP_MEMORY_SCOPE_AGENT) == g) {
        __builtin_amdgcn_s_sleep(1);
      }
    }
    __threadfence();
  }
  __syncthreads();
}

__device__ __forceinline__ float sigmoidf_(float x) {
  return 1.0f / (1.0f + expf(-x));
}

// ---------- K1: x-projections  xiou = emb[sent]@Wioux.T+b ; xf = emb[sent]@Wfx.T+b ----------
#define K1_NT 32
#define K1_CT 48
__global__ __launch_bounds__(256, 1)
void proj_kernel(const int* __restrict__ lsent, const int* __restrict__ rsent,
                 const float* __restrict__ emb,
                 const float* __restrict__ Wioux, const float* __restrict__ bioux,
                 const float* __restrict__ Wfx, const float* __restrict__ bfx,
                 float* __restrict__ xiou, float* __restrict__ xf) {
  __shared__ float xt[K1_NT][300];
  __shared__ float wt[K1_CT][100];
  const int tid = threadIdx.x;
  const int g0 = blockIdx.y * K1_NT;      // global node-id (tree-major, 2048)
  const int c0 = blockIdx.x * K1_CT;      // output col in [0,1200)

  for (int e = tid; e < K1_NT * 300; e += 256) {
    int nn = e / 300, k = e - nn * 300;
    int g = g0 + nn;
    int t = g >> 10, n = g & (NN - 1);
    int s = (t ? rsent : lsent)[n];
    xt[nn][k] = emb[(size_t)s * 300 + k];
  }

  const int a = tid >> 4;   // 0..15 -> nodes {a, a+16}
  const int b = tid & 15;   // 0..15 -> cols {b, b+16, b+32}
  float acc00 = 0, acc01 = 0, acc02 = 0, acc10 = 0, acc11 = 0, acc12 = 0;

  for (int kc = 0; kc < 300; kc += 100) {
    __syncthreads();
    for (int e = tid; e < K1_CT * 100; e += 256) {
      int cc = e / 100, k = e - cc * 100;
      int col = c0 + cc;
      wt[cc][k] = (col < 900) ? Wioux[(size_t)col * 300 + kc + k]
                              : Wfx[(size_t)(col - 900) * 300 + kc + k];
    }
    __syncthreads();
    #pragma unroll
    for (int k4 = 0; k4 < 25; ++k4) {
      float4 x0 = *(const float4*)&xt[a][kc + k4 * 4];
      float4 x1 = *(const float4*)&xt[a + 16][kc + k4 * 4];
      float4 w0 = *(const float4*)&wt[b][k4 * 4];
      float4 w1 = *(const float4*)&wt[b + 16][k4 * 4];
      float4 w2 = *(const float4*)&wt[b + 32][k4 * 4];
      acc00 += x0.x * w0.x + x0.y * w0.y + x0.z * w0.z + x0.w * w0.w;
      acc01 += x0.x * w1.x + x0.y * w1.y + x0.z * w1.z + x0.w * w1.w;
      acc02 += x0.x * w2.x + x0.y * w2.y + x0.z * w2.z + x0.w * w2.w;
      acc10 += x1.x * w0.x + x1.y * w0.y + x1.z * w0.z + x1.w * w0.w;
      acc11 += x1.x * w1.x + x1.y * w1.y + x1.z * w1.z + x1.w * w1.w;
      acc12 += x1.x * w2.x + x1.y * w2.y + x1.z * w2.z + x1.w * w2.w;
    }
  }

  float accs[2][3] = {{acc00, acc01, acc02}, {acc10, acc11, acc12}};
  for (int ni = 0; ni < 2; ++ni) {
    for (int ci = 0; ci < 3; ++ci) {
      int g = g0 + a + 16 * ni;
      int col = c0 + b + 16 * ci;
      int t = g >> 10, n = g & (NN - 1);
      float v = accs[ni][ci];
      if (col < 900) xiou[((size_t)t * NN + n) * 900 + col] = v + bioux[col];
      else           xf[((size_t)t * NN + n) * 300 + (col - 900)] = v + bfx[col - 900];
    }
  }
}

// ---------- K2: level computation + level-parallel tree-LSTM scan ----------
__global__ __launch_bounds__(256, 1)
void scan_kernel(const int* __restrict__ lparents, const int* __restrict__ rparents,
                 const float* __restrict__ Wiouh, const float* __restrict__ biouh,
                 const float* __restrict__ Wfh, const float* __restrict__ bfh,
                 const float* __restrict__ xiou, const float* __restrict__ xf,
                 float* hsum, float* fcsum, float* cbuf,
                 int* lvl, int* lcnt, int* cur, int* chg, int* maxl,
                 int* bar, int* list, float* out) {
  const int tid = threadIdx.x;
  const int t = blockIdx.x / BPT;
  const int b = blockIdx.x - t * BPT;   // 0..BPT-1
  const int colb = b % GB;              // column-slice id
  const int gg = b / GB;                // node-group id 0..NG-1
  const int j0 = colb * SLICE;

  // dot-thread layout: tid<80 : slot = tid>>3 in [0,10), ks = tid&7 -> k-chunk of 38
  const int slot = tid >> 3;
  const int ks = tid & 7;
  const int kk0 = ks * 38;              // 8*38 = 304 >= 300, zero-padded tail
  const bool dotA = (tid < 80);

  const int* parents = t ? rparents : lparents;
  const float* xiouT = xiou + (size_t)t * NN * 900;
  const float* xfT = xf + (size_t)t * NN * MEM;
  float* hsumT = hsum + (size_t)t * NN * MEM;
  float* fcsumT = fcsum + (size_t)t * NN * MEM;
  float* cbufT = cbuf + (size_t)t * NN * MEM;
  float* houtT = out + 5 + (size_t)t * NN * MEM;
  int* lvlT = lvl + t * NN;
  const int* listT = list + t * NN;

  // register-resident weight slices: fully-unrolled, compile-time-indexed loads
  // (runtime-bounded copy loops demote arrays to scratch -- avoid!)
  float w0[38], w1[38], w2[38], w3[38];
  if (dotA) {
    const float* r0 = Wiouh + (size_t)(0 * MEM + j0 + slot) * MEM;
    const float* r1 = Wiouh + (size_t)(1 * MEM + j0 + slot) * MEM;
    const float* r2 = Wiouh + (size_t)(2 * MEM + j0 + slot) * MEM;
    const float* r3 = Wfh + (size_t)(j0 + slot) * MEM;
    #pragma unroll
    for (int i = 0; i < 38; ++i) {
      const int k = kk0 + i;
      const bool ok = (k < 300);
      w0[i] = ok ? r0[ok ? k : 0] : 0.f;
      w1[i] = ok ? r1[ok ? k : 0] : 0.f;
      w2[i] = ok ? r2[ok ? k : 0] : 0.f;
      w3[i] = ok ? r3[ok ? k : 0] : 0.f;
    }
  } else {
    #pragma unroll
    for (int i = 0; i < 38; ++i) { w0[i] = w1[i] = w2[i] = w3[i] = 0.f; }
  }

  __shared__ float vbuf[4][304];
  __shared__ float dots[4][32];
  __shared__ int nodeId[4];
  __shared__ float bI[SLICE], bO[SLICE], bU[SLICE], bF[SLICE];
  __shared__ int offs[MAXLVL];
  __shared__ int cnts[MAXLVL];
  __shared__ int mlS;

  if (tid < SLICE) {
    bI[tid] = biouh[j0 + tid];
    bO[tid] = biouh[300 + j0 + tid];
    bU[tid] = biouh[600 + j0 + tid];
    bF[tid] = bfh[j0 + tid];
  }

  // ---- levels: Bellman-Ford with early exit (lvl[n] = longest chain below n) ----
  const int myn = b * 256 + tid;   // blocks b=0..3 cover all nodes
  for (int iter = 0; iter < MAXLVL; ++iter) {
    if (myn < NN - 1) {
      int L = agloadi(lvlT + myn);
      int v = L + 1;
      int p = parents[myn];
      int old = atomicMax(lvlT + p, v);
      if (old < v) agstorei(chg + t * MAXLVL + iter, 1);
    }
    treebar(bar, t);
    if (agloadi(chg + t * MAXLVL + iter) == 0) break;
  }
  if (myn < NN) {
    int L = min(agloadi(lvlT + myn), MAXLVL - 1);
    atomicMax(maxl + t, L);
    atomicAdd(lcnt + t * MAXLVL + L, 1);
  }
  treebar(bar, t);
  if (tid == 0) mlS = agloadi(maxl + t);
  if (tid < MAXLVL) cnts[tid] = agloadi(lcnt + t * MAXLVL + tid);
  __syncthreads();
  const int ml = mlS;
  if (tid == 0) {
    int run = 0;
    for (int l = 0; l < MAXLVL; ++l) { offs[l] = run; run += cnts[l]; }
  }
  __syncthreads();
  if (myn < NN) {
    int L = min(agloadi(lvlT + myn), MAXLVL - 1);
    int pos = atomicAdd(cur + t * MAXLVL + L, 1);
    agstorei(list + t * NN + offs[L] + pos, myn);
  }
  treebar(bar, t);

  // ---- main level loop: phase L = { B(L-1) ; bar ; A(L) ; bar } ----
  for (int L = 0; L <= ml; ++L) {
    if (L > 0) {
      // B-pass for level L-1: f = sig(Wfh@h + bfh + xf[p]); fcsum[p] += f*c
      const int c0l = offs[L - 1], cn = cnts[L - 1];
      for (int base = gg * 4; base < cn; base += 4 * NG) {
        const int nb = min(4, cn - base);
        if (tid < nb) nodeId[tid] = agloadi(listT + c0l + base + tid);
        for (int e = tid; e < nb * 304; e += 256) {
          int bb = e / 304, k = e - bb * 304;
          int n = agloadi(listT + c0l + base + bb);
          vbuf[bb][k] = (k < MEM) ? agloadf(houtT + (size_t)n * MEM + k) : 0.f;
        }
        __syncthreads();
        if (dotA) {
          for (int bb = 0; bb < nb; ++bb) {
            float acc = 0.f;
            #pragma unroll
            for (int i = 0; i < 38; ++i) acc += w3[i] * vbuf[bb][kk0 + i];
            acc += __shfl_xor(acc, 1);
            acc += __shfl_xor(acc, 2);
            acc += __shfl_xor(acc, 4);
            if (ks == 0) dots[bb][slot] = acc;
          }
        }
        __syncthreads();
        if (tid < nb * SLICE) {
          int bb = tid / SLICE, j = tid - bb * SLICE;
          int n = nodeId[bb];
          int p = parents[n];
          if (p != n) {  // skip root (self-parent; fcsum[root] never read again)
            float f = sigmoidf_(dots[bb][j] + bF[j] + xfT[(size_t)p * MEM + j0 + j]);
            float cadd = f * cbufT[(size_t)n * MEM + j0 + j];
            atomicAdd(fcsumT + (size_t)p * MEM + j0 + j, cadd);
          }
        }
        __syncthreads();
      }
      treebar(bar, t);   // fcsum complete before A(L) reads it (cross node-group)
    }
    // A-pass for level L: iou = xiou[n] + Wiouh@hsum[n] + biouh -> h
    {
      const int c0l = offs[L], cn = cnts[L];
      for (int base = gg * 4; base < cn; base += 4 * NG) {
        const int nb = min(4, cn - base);
        if (tid < nb) nodeId[tid] = agloadi(listT + c0l + base + tid);
        if (L > 0) {
          for (int e = tid; e < nb * 304; e += 256) {
            int bb = e / 304, k = e - bb * 304;
            int n = agloadi(listT + c0l + base + bb);
            vbuf[bb][k] = (k < MEM) ? agloadf(hsumT + (size_t)n * MEM + k) : 0.f;
          }
          __syncthreads();
          if (dotA) {
            for (int bb = 0; bb < nb; ++bb) {
              float aI = 0.f, aO = 0.f, aU = 0.f;
              #pragma unroll
              for (int i = 0; i < 38; ++i) {
                float v = vbuf[bb][kk0 + i];
                aI += w0[i] * v; aO += w1[i] * v; aU += w2[i] * v;
              }
              aI += __shfl_xor(aI, 1); aO += __shfl_xor(aO, 1); aU += __shfl_xor(aU, 1);
              aI += __shfl_xor(aI, 2); aO += __shfl_xor(aO, 2); aU += __shfl_xor(aU, 2);
              aI += __shfl_xor(aI, 4); aO += __shfl_xor(aO, 4); aU += __shfl_xor(aU, 4);
              if (ks == 0) {
                dots[bb][slot] = aI;
                dots[bb][SLICE + slot] = aO;
                dots[bb][2 * SLICE + slot] = aU;
              }
            }
          }
          __syncthreads();
        } else {
          __syncthreads();   // leaves: hsum==0 -> dots==0, skip staging+GEMV
        }
        if (tid < nb * SLICE) {
          int bb = tid / SLICE, j = tid - bb * SLICE;
          int n = nodeId[bb];
          const float* xr = xiouT + (size_t)n * 900;
          float dI = L ? dots[bb][j] : 0.f;
          float dO = L ? dots[bb][SLICE + j] : 0.f;
          float dU = L ? dots[bb][2 * SLICE + j] : 0.f;
          float i_ = sigmoidf_(dI + bI[j] + xr[j0 + j]);
          float o_ = sigmoidf_(dO + bO[j] + xr[300 + j0 + j]);
          float u_ = tanhf(dU + bU[j] + xr[600 + j0 + j]);
          float fc = L ? agloadf(fcsumT + (size_t)n * MEM + j0 + j) : 0.f;
          float c = i_ * u_ + fc;
          float h = o_ * tanhf(c);
          cbufT[(size_t)n * MEM + j0 + j] = c;                 // same-thread reuse in B
          agstoref(houtT + (size_t)n * MEM + j0 + j, h);       // cross-block visible
          int p = parents[n];
          if (p != n) atomicAdd(hsumT + (size_t)p * MEM + j0 + j, h);
        }
        __syncthreads();
      }
    }
    treebar(bar, t);
  }
}

// ---------- K3: similarity head ----------
__global__ __launch_bounds__(256, 1)
void head_kernel(const float* __restrict__ Wwh, const float* __restrict__ bwh,
                 const float* __restrict__ Wwp, const float* __restrict__ bwp,
                 float* out) {
  __shared__ float vd[600];
  __shared__ float hid[200];
  __shared__ float sL[5];
  const int tid = threadIdx.x;
  for (int e = tid; e < 300; e += 256) {
    float lv = out[5 + 1023 * 300 + e];
    float rv = out[5 + 307200 + 1023 * 300 + e];
    vd[e] = lv * rv;
    vd[300 + e] = fabsf(lv - rv);
  }
  __syncthreads();
  if (tid < 200) {
    float acc = bwh[tid];
    const float* wr = Wwh + (size_t)tid * 600;
    for (int k = 0; k < 600; ++k) acc += vd[k] * wr[k];
    hid[tid] = sigmoidf_(acc);
  }
  __syncthreads();
  if (tid < 5) {
    float acc = bwp[tid];
    const float* wr = Wwp + (size_t)tid * 200;
    for (int k = 0; k < 200; ++k) acc += hid[k] * wr[k];
    sL[tid] = acc;
  }
  __syncthreads();
  if (tid == 0) {
    float m = sL[0];
    for (int c = 1; c < 5; ++c) m = fmaxf(m, sL[c]);
    float s = 0.f;
    for (int c = 0; c < 5; ++c) s += expf(sL[c] - m);
    float lz = m + logf(s);
    for (int c = 0; c < 5; ++c) out[c] = sL[c] - lz;
  }
}

extern "C" void kernel_launch(void* const* d_in, const int* in_sizes, int n_in,
                              void* d_out, int out_size, void* d_ws, size_t ws_size,
                              hipStream_t stream) {
  const int* lsent = (const int*)d_in[0];
  const int* lparents = (const int*)d_in[1];
  const int* rsent = (const int*)d_in[2];
  const int* rparents = (const int*)d_in[3];
  // d_in[4] = calculate_sim (unused)
  const float* emb = (const float*)d_in[5];
  const float* Wioux = (const float*)d_in[6];
  const float* bioux = (const float*)d_in[7];
  const float* Wiouh = (const float*)d_in[8];
  const float* biouh = (const float*)d_in[9];
  const float* Wfx = (const float*)d_in[10];
  const float* bfx = (const float*)d_in[11];
  const float* Wfh = (const float*)d_in[12];
  const float* bfh = (const float*)d_in[13];
  const float* Wwh = (const float*)d_in[14];
  const float* bwh = (const float*)d_in[15];
  const float* Wwp = (const float*)d_in[16];
  const float* bwp = (const float*)d_in[17];
  float* out = (float*)d_out;

  char* ws = (char*)d_ws;
  float* hsum = (float*)(ws);                    // 2*1024*300 f  (zeroed)
  float* fcsum = (float*)(ws + 2457600);         // 2*1024*300 f  (zeroed)
  int* lvl = (int*)(ws + 4915200);               // 2048 i        (zeroed)
  int* lcnt = (int*)(ws + 4923392);              // 128 i         (zeroed)
  int* cur = (int*)(ws + 4923904);               // 128 i         (zeroed)
  int* chg = (int*)(ws + 4924416);               // 128 i         (zeroed)
  int* maxl = (int*)(ws + 4924928);              // 2 i + pad     (zeroed)
  int* bar = (int*)(ws + 4924992);               // 64 i          (zeroed)
  float* xiou = (float*)(ws + 4925440);          // 2*1024*900 f
  float* xf = (float*)(ws + 12298240);           // 2*1024*300 f
  float* cbuf = (float*)(ws + 14755840);         // 2*1024*300 f
  int* list = (int*)(ws + 17213440);             // 2048 i

  hipMemsetAsync(d_ws, 0, 4925248, stream);
  proj_kernel<<<dim3(25, 64), 256, 0, stream>>>(lsent, rsent, emb, Wioux, bioux,
                                                Wfx, bfx, xiou, xf);
  scan_kernel<<<2 * BPT, 256, 0, stream>>>(lparents, rparents, Wiouh, biouh, Wfh, bfh,
                                           xiou, xf, hsum, fcsum, cbuf,
                                           lvl, lcnt, cur, chg, maxl, bar, list, out);
  head_kernel<<<1, 256, 0, stream>>>(Wwh, bwh, Wwp, bwp, out);
}

// Round 4
// 1037.419 us; speedup vs baseline: 3.4217x; 1.8555x over previous
//
#include <hip/hip_runtime.h>
#include <math.h>

#define NN 1024
#define MEM 300
#define SLICE 20       // j columns per column-slice block
#define GB 15          // column-slice blocks per (tree, node-group): 15*20 = 300
#define NG 8           // node-group parallelism per tree
#define BPT (GB * NG)  // blocks per tree = 120
#define SCAN_T 512

// ---------- agent-scope helpers (cross-XCD safe) ----------
__device__ __forceinline__ float agloadf(const float* p) {
  return __hip_atomic_load(p, __ATOMIC_RELAXED, __HIP_MEMORY_SCOPE_AGENT);
}
__device__ __forceinline__ void agstoref(float* p, float v) {
  __hip_atomic_store(p, v, __ATOMIC_RELAXED, __HIP_MEMORY_SCOPE_AGENT);
}

// per-tree grid barrier over BPT blocks
__device__ __forceinline__ void treebar(int* bar, int t) {
  __syncthreads();
  if (threadIdx.x == 0) {
    int* cnt = bar + t * 32;
    int* gen = bar + t * 32 + 16;
    __threadfence();
    int g = __hip_atomic_load(gen, __ATOMIC_RELAXED, __HIP_MEMORY_SCOPE_AGENT);
    int v = __hip_atomic_fetch_add(cnt, 1, __ATOMIC_ACQ_REL, __HIP_MEMORY_SCOPE_AGENT);
    if (v == BPT - 1) {
      __hip_atomic_store(cnt, 0, __ATOMIC_RELAXED, __HIP_MEMORY_SCOPE_AGENT);
      __hip_atomic_fetch_add(gen, 1, __ATOMIC_RELEASE, __HIP_MEMORY_SCOPE_AGENT);
    } else {
      while (__hip_atomic_load(gen, __ATOMIC_ACQUIRE, __HIP_MEMORY_SCOPE_AGENT) == g) {
        __builtin_amdgcn_s_sleep(2);
      }
    }
    __threadfence();
  }
  __syncthreads();
}

__device__ __forceinline__ float sigmoidf_(float x) {
  return 1.0f / (1.0f + expf(-x));
}

// ---------- K0: levels + per-level node lists + children CSR (LDS-only BF) ----------
__global__ __launch_bounds__(1024, 1)
void levels_kernel(const int* __restrict__ lparents, const int* __restrict__ rparents,
                   int* __restrict__ list, int* __restrict__ offsG, int* __restrict__ mlG,
                   int* __restrict__ childOff, int* __restrict__ childList) {
  const int t = blockIdx.x;
  const int* par = t ? rparents : lparents;
  const int n = threadIdx.x;
  __shared__ int lvlS[NN];
  __shared__ int aux[NN];
  __shared__ int coff[NN];
  __shared__ int cnts[64];
  __shared__ int offsS[65];
  __shared__ int curL[64];
  __shared__ int chunk[32];
  __shared__ int flagS;
  const int p = par[n];
  lvlS[n] = 0; aux[n] = 0;
  if (n < 64) { cnts[n] = 0; curL[n] = 0; }
  __syncthreads();
  for (int it = 0; it < 64; ++it) {
    if (n == 0) flagS = 0;
    __syncthreads();
    if (n < NN - 1) {
      int v = lvlS[n] + 1;
      int old = atomicMax(&lvlS[p], v);
      if (old < v) flagS = 1;
    }
    __syncthreads();
    if (!flagS) break;
  }
  const int L = lvlS[n];
  atomicAdd(&cnts[L], 1);
  if (n < NN - 1) atomicAdd(&aux[p], 1);
  __syncthreads();
  if (n == 0) {
    int acc = 0;
    for (int l = 0; l < 64; ++l) { offsS[l] = acc; acc += cnts[l]; }
    offsS[64] = acc;
    mlG[t] = lvlS[NN - 1];   // root carries the max level
  }
  __syncthreads();
  { int pos = atomicAdd(&curL[L], 1); list[t * NN + offsS[L] + pos] = n; }
  // exclusive prefix of child counts -> children CSR offsets
  if (n < 32) { int s = 0; for (int i = 0; i < 32; ++i) s += aux[n * 32 + i]; chunk[n] = s; }
  __syncthreads();
  if (n == 0) { int acc = 0; for (int i = 0; i < 32; ++i) { int s = chunk[i]; chunk[i] = acc; acc += s; } }
  __syncthreads();
  if (n < 32) { int acc = chunk[n]; for (int i = 0; i < 32; ++i) { coff[n * 32 + i] = acc; acc += aux[n * 32 + i]; } }
  __syncthreads();
  childOff[t * (NN + 1) + n] = coff[n];
  if (n == 0) childOff[t * (NN + 1) + NN] = NN - 1;
  aux[n] = 0;
  __syncthreads();
  if (n < NN - 1) { int idx = coff[p] + atomicAdd(&aux[p], 1); childList[t * NN + idx] = n; }
  if (n < 65) offsG[t * 65 + n] = offsS[n];
}

// ---------- K1: x-projections ----------
#define K1_NT 32
#define K1_CT 48
__global__ __launch_bounds__(256, 1)
void proj_kernel(const int* __restrict__ lsent, const int* __restrict__ rsent,
                 const float* __restrict__ emb,
                 const float* __restrict__ Wioux, const float* __restrict__ bioux,
                 const float* __restrict__ Wfx, const float* __restrict__ bfx,
                 float* __restrict__ xiou, float* __restrict__ xf) {
  __shared__ float xt[K1_NT][300];
  __shared__ float wt[K1_CT][100];
  const int tid = threadIdx.x;
  const int g0 = blockIdx.y * K1_NT;
  const int c0 = blockIdx.x * K1_CT;

  for (int e = tid; e < K1_NT * 300; e += 256) {
    int nn = e / 300, k = e - nn * 300;
    int g = g0 + nn;
    int t = g >> 10, n = g & (NN - 1);
    int s = (t ? rsent : lsent)[n];
    xt[nn][k] = emb[(size_t)s * 300 + k];
  }

  const int a = tid >> 4;
  const int b = tid & 15;
  float acc00 = 0, acc01 = 0, acc02 = 0, acc10 = 0, acc11 = 0, acc12 = 0;

  for (int kc = 0; kc < 300; kc += 100) {
    __syncthreads();
    for (int e = tid; e < K1_CT * 100; e += 256) {
      int cc = e / 100, k = e - cc * 100;
      int col = c0 + cc;
      wt[cc][k] = (col < 900) ? Wioux[(size_t)col * 300 + kc + k]
                              : Wfx[(size_t)(col - 900) * 300 + kc + k];
    }
    __syncthreads();
    #pragma unroll
    for (int k4 = 0; k4 < 25; ++k4) {
      float4 x0 = *(const float4*)&xt[a][kc + k4 * 4];
      float4 x1 = *(const float4*)&xt[a + 16][kc + k4 * 4];
      float4 w0 = *(const float4*)&wt[b][k4 * 4];
      float4 w1 = *(const float4*)&wt[b + 16][k4 * 4];
      float4 w2 = *(const float4*)&wt[b + 32][k4 * 4];
      acc00 += x0.x * w0.x + x0.y * w0.y + x0.z * w0.z + x0.w * w0.w;
      acc01 += x0.x * w1.x + x0.y * w1.y + x0.z * w1.z + x0.w * w1.w;
      acc02 += x0.x * w2.x + x0.y * w2.y + x0.z * w2.z + x0.w * w2.w;
      acc10 += x1.x * w0.x + x1.y * w0.y + x1.z * w0.z + x1.w * w0.w;
      acc11 += x1.x * w1.x + x1.y * w1.y + x1.z * w1.z + x1.w * w1.w;
      acc12 += x1.x * w2.x + x1.y * w2.y + x1.z * w2.z + x1.w * w2.w;
    }
  }

  float accs[2][3] = {{acc00, acc01, acc02}, {acc10, acc11, acc12}};
  for (int ni = 0; ni < 2; ++ni) {
    for (int ci = 0; ci < 3; ++ci) {
      int g = g0 + a + 16 * ni;
      int col = c0 + b + 16 * ci;
      int t = g >> 10, n = g & (NN - 1);
      float v = accs[ni][ci];
      if (col < 900) xiou[((size_t)t * NN + n) * 900 + col] = v + bioux[col];
      else           xf[((size_t)t * NN + n) * 300 + (col - 900)] = v + bfx[col - 900];
    }
  }
}

// ---------- K2: pull-based level-parallel tree-LSTM (one barrier per level) ----------
__global__ __launch_bounds__(SCAN_T, 1)
void scan_kernel(const float* __restrict__ Wiouh, const float* __restrict__ biouh,
                 const float* __restrict__ Wfh, const float* __restrict__ bfh,
                 const float* __restrict__ xiou, const float* __restrict__ xf,
                 const int* __restrict__ list, const int* __restrict__ offsG,
                 const int* __restrict__ mlG, const int* __restrict__ childOff,
                 const int* __restrict__ childList,
                 float* cbuf, int* bar, float* out) {
  const int tid = threadIdx.x;
  const int t = blockIdx.x / BPT;
  const int b = blockIdx.x % BPT;
  const int colb = b % GB;
  const int gg = b / GB;
  const int j0 = colb * SLICE;

  const int slot = tid >> 4;        // 0..31 (weights valid for slot<20 i.e. tid<320)
  const int ks = tid & 15;          // 16 k-chunks of 19 (16*19=304, zero-padded)
  const int kk0 = ks * 19;
  const bool dotT = (tid < 320);

  const float* xiouT = xiou + (size_t)t * NN * 900;
  const float* xfT = xf + (size_t)t * NN * MEM;
  float* cbufT = cbuf + (size_t)t * NN * MEM;
  float* hT = out + 5 + (size_t)t * NN * MEM;
  const int* listT = list + t * NN;
  const int* coT = childOff + t * (NN + 1);
  const int* clT = childList + t * NN;

  // register-resident weight slices (compile-time indexed only)
  float w0[19], w1[19], w2[19], w3[19];
  if (dotT) {
    const float* r0 = Wiouh + (size_t)(j0 + slot) * MEM;
    const float* r1 = Wiouh + (size_t)(MEM + j0 + slot) * MEM;
    const float* r2 = Wiouh + (size_t)(2 * MEM + j0 + slot) * MEM;
    const float* r3 = Wfh + (size_t)(j0 + slot) * MEM;
    #pragma unroll
    for (int i = 0; i < 19; ++i) {
      const int k = kk0 + i;
      const bool ok = (k < 300);
      const int kc = ok ? k : 0;
      w0[i] = ok ? r0[kc] : 0.f;
      w1[i] = ok ? r1[kc] : 0.f;
      w2[i] = ok ? r2[kc] : 0.f;
      w3[i] = ok ? r3[kc] : 0.f;
    }
  } else {
    #pragma unroll
    for (int i = 0; i < 19; ++i) { w0[i] = w1[i] = w2[i] = w3[i] = 0.f; }
  }

  __shared__ float vb[4][304];
  __shared__ float hsumS[4][304];
  __shared__ float fcS[4][SLICE];
  __shared__ float xiS[4][3][SLICE];
  __shared__ float xfS[4][SLICE];
  __shared__ float cslc[4][SLICE];
  __shared__ float dfS[4][SLICE];
  __shared__ float dIS[4][SLICE], dOS[4][SLICE], dUS[4][SLICE];
  __shared__ int nodeId[4], cS_[4], cE_[4], fOff[5], bbc[4], chc[4];
  __shared__ int offsS[65];
  __shared__ float bI[SLICE], bO[SLICE], bU[SLICE], bF[SLICE];

  if (tid < SLICE) {
    bI[tid] = biouh[j0 + tid];
    bO[tid] = biouh[300 + j0 + tid];
    bU[tid] = biouh[600 + j0 + tid];
    bF[tid] = bfh[j0 + tid];
  }
  if (tid < 65) offsS[tid] = offsG[t * 65 + tid];
  __syncthreads();
  const int ml = mlG[t];

  // ---- level 0: leaves, pointwise only ----
  {
    const int c0l = offsS[0], cn = offsS[1] - offsS[0];
    for (int base = gg * 24; base < cn; base += 24 * NG) {
      const int nb = min(24, cn - base);
      if (tid < nb * SLICE) {
        int bb = tid / SLICE, j = tid - bb * SLICE;
        int n = listT[c0l + base + bb];
        const float* xr = xiouT + (size_t)n * 900;
        float i_ = sigmoidf_(xr[j0 + j] + bI[j]);
        float o_ = sigmoidf_(xr[300 + j0 + j] + bO[j]);
        float u_ = tanhf(xr[600 + j0 + j] + bU[j]);
        float c = i_ * u_;
        float h = o_ * tanhf(c);
        agstoref(&cbufT[(size_t)n * MEM + j0 + j], c);
        agstoref(&hT[(size_t)n * MEM + j0 + j], h);
      }
    }
    treebar(bar, t);
  }

  // ---- levels 1..ml: pull children's h, fuse hsum + fc, one barrier/level ----
  for (int L = 1; L <= ml; ++L) {
    const int c0l = offsS[L], cn = offsS[L + 1] - offsS[L];
    for (int base = gg * 4; base < cn; base += 4 * NG) {
      const int nb = min(4, cn - base);
      for (int e = tid; e < 4 * 304; e += SCAN_T) ((float*)hsumS)[e] = 0.f;
      if (tid < 4 * SLICE) ((float*)fcS)[tid] = 0.f;
      if (tid < nb) {
        int n = listT[c0l + base + tid];
        nodeId[tid] = n;
        cS_[tid] = coT[n];
        cE_[tid] = coT[n + 1];
      }
      __syncthreads();
      if (tid == 0) {
        int acc = 0;
        for (int bb = 0; bb < nb; ++bb) { fOff[bb] = acc; acc += cE_[bb] - cS_[bb]; }
        fOff[nb] = acc;
      }
      for (int e = tid; e < nb * 3 * SLICE; e += SCAN_T) {
        int bb = e / (3 * SLICE), r = e % (3 * SLICE), g = r / SLICE, j = r % SLICE;
        xiS[bb][g][j] = xiouT[(size_t)nodeId[bb] * 900 + g * 300 + j0 + j];
      }
      if (tid < nb * SLICE) {
        int bb = tid / SLICE, j = tid % SLICE;
        xfS[bb][j] = xfT[(size_t)nodeId[bb] * MEM + j0 + j];
      }
      __syncthreads();
      const int tc = fOff[nb];
      for (int cs = 0; cs < tc; cs += 4) {
        const int nc = min(4, tc - cs);
        if (tid < nc) {
          int idx = cs + tid, bb = 0;
          while (idx >= fOff[bb + 1]) ++bb;
          bbc[tid] = bb;
          chc[tid] = clT[cS_[bb] + idx - fOff[bb]];
        }
        __syncthreads();
        for (int e = tid; e < nc * 304; e += SCAN_T) {
          int cc = e / 304, k = e - cc * 304;
          vb[cc][k] = (k < 300) ? agloadf(&hT[(size_t)chc[cc] * MEM + k]) : 0.f;
        }
        if (tid < nc * SLICE) {
          int cc = tid / SLICE, j = tid % SLICE;
          cslc[cc][j] = agloadf(&cbufT[(size_t)chc[cc] * MEM + j0 + j]);
        }
        __syncthreads();
        if (dotT) {
          for (int cc = 0; cc < nc; ++cc) {
            float a = 0.f;
            #pragma unroll
            for (int i = 0; i < 19; ++i) a += w3[i] * vb[cc][kk0 + i];
            a += __shfl_xor(a, 1); a += __shfl_xor(a, 2);
            a += __shfl_xor(a, 4); a += __shfl_xor(a, 8);
            if (ks == 0) dfS[cc][slot] = a;
          }
        } else {
          for (int k = tid - 320; k < 304; k += 192)
            for (int cc = 0; cc < nc; ++cc) hsumS[bbc[cc]][k] += vb[cc][k];
        }
        __syncthreads();
        if (tid < nc * SLICE) {
          int cc = tid / SLICE, j = tid % SLICE, bb = bbc[cc];
          float f = sigmoidf_(dfS[cc][j] + bF[j] + xfS[bb][j]);
          atomicAdd(&fcS[bb][j], f * cslc[cc][j]);
        }
        __syncthreads();
      }
      if (dotT) {
        for (int bb = 0; bb < nb; ++bb) {
          float aI = 0.f, aO = 0.f, aU = 0.f;
          #pragma unroll
          for (int i = 0; i < 19; ++i) {
            float v = hsumS[bb][kk0 + i];
            aI += w0[i] * v; aO += w1[i] * v; aU += w2[i] * v;
          }
          aI += __shfl_xor(aI, 1); aO += __shfl_xor(aO, 1); aU += __shfl_xor(aU, 1);
          aI += __shfl_xor(aI, 2); aO += __shfl_xor(aO, 2); aU += __shfl_xor(aU, 2);
          aI += __shfl_xor(aI, 4); aO += __shfl_xor(aO, 4); aU += __shfl_xor(aU, 4);
          aI += __shfl_xor(aI, 8); aO += __shfl_xor(aO, 8); aU += __shfl_xor(aU, 8);
          if (ks == 0) { dIS[bb][slot] = aI; dOS[bb][slot] = aO; dUS[bb][slot] = aU; }
        }
      }
      __syncthreads();
      if (tid < nb * SLICE) {
        int bb = tid / SLICE, j = tid % SLICE;
        int n = nodeId[bb];
        float i_ = sigmoidf_(dIS[bb][j] + bI[j] + xiS[bb][0][j]);
        float o_ = sigmoidf_(dOS[bb][j] + bO[j] + xiS[bb][1][j]);
        float u_ = tanhf(dUS[bb][j] + bU[j] + xiS[bb][2][j]);
        float c = i_ * u_ + fcS[bb][j];
        float h = o_ * tanhf(c);
        agstoref(&cbufT[(size_t)n * MEM + j0 + j], c);
        agstoref(&hT[(size_t)n * MEM + j0 + j], h);
      }
      __syncthreads();
    }
    treebar(bar, t);
  }
}

// ---------- K3: similarity head ----------
__global__ __launch_bounds__(256, 1)
void head_kernel(const float* __restrict__ Wwh, const float* __restrict__ bwh,
                 const float* __restrict__ Wwp, const float* __restrict__ bwp,
                 float* out) {
  __shared__ float vd[600];
  __shared__ float hid[200];
  __shared__ float sL[5];
  const int tid = threadIdx.x;
  for (int e = tid; e < 300; e += 256) {
    float lv = out[5 + 1023 * 300 + e];
    float rv = out[5 + 307200 + 1023 * 300 + e];
    vd[e] = lv * rv;
    vd[300 + e] = fabsf(lv - rv);
  }
  __syncthreads();
  if (tid < 200) {
    float acc = bwh[tid];
    const float* wr = Wwh + (size_t)tid * 600;
    for (int k = 0; k < 600; ++k) acc += vd[k] * wr[k];
    hid[tid] = sigmoidf_(acc);
  }
  __syncthreads();
  if (tid < 5) {
    float acc = bwp[tid];
    const float* wr = Wwp + (size_t)tid * 200;
    for (int k = 0; k < 200; ++k) acc += hid[k] * wr[k];
    sL[tid] = acc;
  }
  __syncthreads();
  if (tid == 0) {
    float m = sL[0];
    for (int c = 1; c < 5; ++c) m = fmaxf(m, sL[c]);
    float s = 0.f;
    for (int c = 0; c < 5; ++c) s += expf(sL[c] - m);
    float lz = m + logf(s);
    for (int c = 0; c < 5; ++c) out[c] = sL[c] - lz;
  }
}

extern "C" void kernel_launch(void* const* d_in, const int* in_sizes, int n_in,
                              void* d_out, int out_size, void* d_ws, size_t ws_size,
                              hipStream_t stream) {
  const int* lsent = (const int*)d_in[0];
  const int* lparents = (const int*)d_in[1];
  const int* rsent = (const int*)d_in[2];
  const int* rparents = (const int*)d_in[3];
  const float* emb = (const float*)d_in[5];
  const float* Wioux = (const float*)d_in[6];
  const float* bioux = (const float*)d_in[7];
  const float* Wiouh = (const float*)d_in[8];
  const float* biouh = (const float*)d_in[9];
  const float* Wfx = (const float*)d_in[10];
  const float* bfx = (const float*)d_in[11];
  const float* Wfh = (const float*)d_in[12];
  const float* bfh = (const float*)d_in[13];
  const float* Wwh = (const float*)d_in[14];
  const float* bwh = (const float*)d_in[15];
  const float* Wwp = (const float*)d_in[16];
  const float* bwp = (const float*)d_in[17];
  float* out = (float*)d_out;

  char* ws = (char*)d_ws;
  int* bar = (int*)(ws);                         // 256 B (zeroed)
  float* cbuf = (float*)(ws + 256);              // 2*1024*300 f
  int* list = (int*)(ws + 2457856);              // 2048 i
  int* offsG = (int*)(ws + 2466048);             // 2*65 i
  int* mlG = (int*)(ws + 2466816);               // 2 i
  int* childOff = (int*)(ws + 2467072);          // 2*1025 i
  int* childList = (int*)(ws + 2475520);         // 2048 i
  float* xiou = (float*)(ws + 2483712);          // 2*1024*900 f
  float* xf = (float*)(ws + 9856512);            // 2*1024*300 f

  hipMemsetAsync(ws, 0, 256, stream);
  levels_kernel<<<2, 1024, 0, stream>>>(lparents, rparents, list, offsG, mlG,
                                        childOff, childList);
  proj_kernel<<<dim3(25, 64), 256, 0, stream>>>(lsent, rsent, emb, Wioux, bioux,
                                                Wfx, bfx, xiou, xf);
  scan_kernel<<<2 * BPT, SCAN_T, 0, stream>>>(Wiouh, biouh, Wfh, bfh, xiou, xf,
                                              list, offsG, mlG, childOff, childList,
                                              cbuf, bar, out);
  head_kernel<<<1, 256, 0, stream>>>(Wwh, bwh, Wwp, bwp, out);
}